// Round 1
// baseline (194.114 us; speedup 1.0000x reference)
//
#include <hip/hip_runtime.h>
#include <math.h>

#define BB 2
#define LL 8
#define HH 240
#define WW 320
#define NN (HH*WW)      // 76800
#define MM (LL*NN)      // 614400

#define DIST_TH 0.05f
#define DOT_TH  0.9396926207859084f   // cos(20 deg)
#define SIGMA   0.6f
#define EPSF    1e-8f
#define SENTINEL 0x7F7F7F7F

// ---------------------------------------------------------------------------
// Frame-data helper: backproject pixel (h,w) of frame (b,s) to world (pw),
// compute forward-difference normal, color, alpha, validity.
// ---------------------------------------------------------------------------
__device__ __forceinline__ float backproject(
    const float* __restrict__ dep,   // depth[b][s] base, NN floats
    float fx, float fy, float cx, float cy,
    const float* __restrict__ P,     // pose[b][s], 16 floats row-major
    int h, int w, float o[3])
{
    float d  = dep[h*WW + w];
    float gx = ((float)w - cx) / fx;
    float gy = ((float)h - cy) / fy;
    float px = gx*d, py = gy*d, pz = d;
    o[0] = P[0]*px + P[1]*py + P[2]*pz  + P[3];
    o[1] = P[4]*px + P[5]*py + P[6]*pz  + P[7];
    o[2] = P[8]*px + P[9]*py + P[10]*pz + P[11];
    return d;
}

__device__ __forceinline__ void frame_data(
    const float* __restrict__ rgb, const float* __restrict__ depth,
    const float* __restrict__ intr, const float* __restrict__ poses,
    int b, int s, int n,
    float fpos[3], float fn[3], float fcol[3], float& falpha, bool& fvalid)
{
    const float* Km = intr + b*16;
    float fx = Km[0], fy = Km[5], cx = Km[2], cy = Km[6];
    const float* P  = poses + (b*LL + s)*16;
    const float* dep = depth + ((size_t)(b*LL + s))*NN;

    int h = n / WW, w = n % WW;

    float p0[3], tmp[3], dx[3], dy[3];
    float d = backproject(dep, fx, fy, cx, cy, P, h, w, p0);

    if (w < WW-1) { backproject(dep, fx, fy, cx, cy, P, h, w+1, tmp);
                    dx[0]=tmp[0]-p0[0]; dx[1]=tmp[1]-p0[1]; dx[2]=tmp[2]-p0[2]; }
    else          { backproject(dep, fx, fy, cx, cy, P, h, WW-2, tmp);
                    dx[0]=p0[0]-tmp[0]; dx[1]=p0[1]-tmp[1]; dx[2]=p0[2]-tmp[2]; }

    if (h < HH-1) { backproject(dep, fx, fy, cx, cy, P, h+1, w, tmp);
                    dy[0]=tmp[0]-p0[0]; dy[1]=tmp[1]-p0[1]; dy[2]=tmp[2]-p0[2]; }
    else          { backproject(dep, fx, fy, cx, cy, P, HH-2, w, tmp);
                    dy[0]=p0[0]-tmp[0]; dy[1]=p0[1]-tmp[1]; dy[2]=p0[2]-tmp[2]; }

    float nx = dx[1]*dy[2] - dx[2]*dy[1];
    float ny = dx[2]*dy[0] - dx[0]*dy[2];
    float nz = dx[0]*dy[1] - dx[1]*dy[0];
    float nl = sqrtf(nx*nx + ny*ny + nz*nz) + EPSF;
    fn[0] = nx/nl; fn[1] = ny/nl; fn[2] = nz/nl;

    fpos[0]=p0[0]; fpos[1]=p0[1]; fpos[2]=p0[2];

    const float* c = rgb + (((size_t)(b*LL + s))*NN + n)*3;
    fcol[0]=c[0]; fcol[1]=c[1]; fcol[2]=c[2];

    float gx = ((float)w - cx)/fx, gy = ((float)h - cy)/fy;
    falpha = expf(-(gx*gx + gy*gy) / (2.0f*SIGMA*SIGMA));
    fvalid = d > 0.0f;
}

// ---------------------------------------------------------------------------
// Kernel 1: initialize map. Rows [0,N) get frame-0 features, rest zeros.
// ---------------------------------------------------------------------------
__global__ __launch_bounds__(256) void k_init(
    const float* __restrict__ rgb, const float* __restrict__ depth,
    const float* __restrict__ intr, const float* __restrict__ poses,
    float* __restrict__ map)
{
    int b = blockIdx.y;
    int m = blockIdx.x*blockDim.x + threadIdx.x;
    if (m >= MM) return;
    float* row = map + ((size_t)b*MM + m)*10;
    if (m >= NN) {
        #pragma unroll
        for (int k=0;k<10;k++) row[k]=0.0f;
        return;
    }
    float fpos[3], fn[3], fcol[3], falpha; bool fvalid;
    frame_data(rgb, depth, intr, poses, b, 0, m, fpos, fn, fcol, falpha, fvalid);
    if (fvalid) {
        row[0]=fpos[0]; row[1]=fpos[1]; row[2]=fpos[2];
        row[3]=fn[0];   row[4]=fn[1];   row[5]=fn[2];
        row[6]=fcol[0]; row[7]=fcol[1]; row[8]=fcol[2];
        row[9]=falpha;
    } else {
        #pragma unroll
        for (int k=0;k<10;k++) row[k]=0.0f;
    }
}

// ---------------------------------------------------------------------------
// Kernel 2 (per step s): project map points [0, s*N) into frame s,
// scatter-min winning map index per pixel.
// ---------------------------------------------------------------------------
__global__ __launch_bounds__(256) void k_project(
    const float* __restrict__ intr, const float* __restrict__ poses,
    const float* __restrict__ map, int* __restrict__ corr, int s)
{
    int b = blockIdx.y;
    int i = blockIdx.x*blockDim.x + threadIdx.x;
    int limit = s*NN;
    if (i >= limit) return;

    const float* row = map + ((size_t)b*MM + i)*10;
    float conf = row[9];
    if (!(conf > 0.0f)) return;

    const float* Km = intr + b*16;
    float fx = Km[0], fy = Km[5], cx = Km[2], cy = Km[6];
    const float* P  = poses + (b*LL + s)*16;

    // pc = (mpos - t) @ R  -> pc[k] = sum_j (m[j]-t[j]) * R[j][k]
    float d0 = row[0]-P[3], d1 = row[1]-P[7], d2 = row[2]-P[11];
    float pcx = d0*P[0] + d1*P[4] + d2*P[8];
    float pcy = d0*P[1] + d1*P[5] + d2*P[9];
    float pcz = d0*P[2] + d1*P[6] + d2*P[10];
    if (!(pcz > EPSF)) return;

    float uf = rintf(fx*pcx/pcz + cx);   // round half-to-even, matches jnp.round
    float vf = rintf(fy*pcy/pcz + cy);
    if (!(uf >= 0.0f && uf <= (float)(WW-1) && vf >= 0.0f && vf <= (float)(HH-1))) return;
    int ui = (int)uf, vi = (int)vf;
    atomicMin(&corr[b*NN + vi*WW + ui], i);
}

// ---------------------------------------------------------------------------
// Kernel 3 (per step s): per pixel, fuse matched map row and append frame
// features to slots [s*N, (s+1)*N). Also resets corr[n] for the next step.
// ---------------------------------------------------------------------------
__global__ __launch_bounds__(256) void k_fuse(
    const float* __restrict__ rgb, const float* __restrict__ depth,
    const float* __restrict__ intr, const float* __restrict__ poses,
    float* __restrict__ map, int* __restrict__ corr, int s)
{
    int b = blockIdx.y;
    int n = blockIdx.x*blockDim.x + threadIdx.x;
    if (n >= NN) return;

    float fpos[3], fn[3], fcol[3], falpha; bool fvalid;
    frame_data(rgb, depth, intr, poses, b, s, n, fpos, fn, fcol, falpha, fvalid);

    int cv = corr[b*NN + n];
    corr[b*NN + n] = SENTINEL;   // owned by this thread only; reset for next step

    bool match = false;
    if (cv < MM && fvalid) {
        int ci = cv;             // unique across threads (one winner per pixel)
        float* crow = map + ((size_t)b*MM + ci)*10;
        float cp0=crow[0], cp1=crow[1], cp2=crow[2];
        float cn0=crow[3], cn1=crow[4], cn2=crow[5];
        float cc0=crow[6], cc1=crow[7], cc2=crow[8];
        float cw = crow[9];

        float e0 = fpos[0]-cp0, e1 = fpos[1]-cp1, e2 = fpos[2]-cp2;
        float dist = sqrtf(e0*e0 + e1*e1 + e2*e2);
        float dotp = fn[0]*cn0 + fn[1]*cn1 + fn[2]*cn2;

        if (dist < DIST_TH && dotp > DOT_TH) {
            match = true;
            float wgt = falpha;
            float den = cw + wgt;
            float np0 = (cw*cp0 + wgt*fpos[0]) / den;
            float np1 = (cw*cp1 + wgt*fpos[1]) / den;
            float np2 = (cw*cp2 + wgt*fpos[2]) / den;
            float nc0 = (cw*cc0 + wgt*fcol[0]) / den;
            float nc1 = (cw*cc1 + wgt*fcol[1]) / den;
            float nc2 = (cw*cc2 + wgt*fcol[2]) / den;
            float nn0 = cw*cn0 + wgt*fn[0];
            float nn1 = cw*cn1 + wgt*fn[1];
            float nn2 = cw*cn2 + wgt*fn[2];
            float nl  = sqrtf(nn0*nn0 + nn1*nn1 + nn2*nn2) + EPSF;
            crow[0]=np0; crow[1]=np1; crow[2]=np2;
            crow[3]=nn0/nl; crow[4]=nn1/nl; crow[5]=nn2/nl;
            crow[6]=nc0; crow[7]=nc1; crow[8]=nc2;
            crow[9]=den;
        }
    }

    float* srow = map + ((size_t)b*MM + (size_t)s*NN + n)*10;
    bool app = fvalid && !match;
    if (app) {
        srow[0]=fpos[0]; srow[1]=fpos[1]; srow[2]=fpos[2];
        srow[3]=fn[0];   srow[4]=fn[1];   srow[5]=fn[2];
        srow[6]=fcol[0]; srow[7]=fcol[1]; srow[8]=fcol[2];
        srow[9]=falpha;
    } else {
        #pragma unroll
        for (int k=0;k<10;k++) srow[k]=0.0f;
    }
}

// ---------------------------------------------------------------------------
extern "C" void kernel_launch(void* const* d_in, const int* in_sizes, int n_in,
                              void* d_out, int out_size, void* d_ws, size_t ws_size,
                              hipStream_t stream) {
    const float* rgb   = (const float*)d_in[0];  // (B,L,H,W,3)
    const float* depth = (const float*)d_in[1];  // (B,L,H,W,1)
    const float* intr  = (const float*)d_in[2];  // (B,1,4,4)
    const float* poses = (const float*)d_in[3];  // (B,L,4,4)
    float* map = (float*)d_out;                  // (B,M,10)
    int*   corr = (int*)d_ws;                    // B*N ints

    hipMemsetAsync(corr, 0x7F, (size_t)BB*NN*sizeof(int), stream);

    dim3 blk(256);
    k_init<<<dim3((MM+255)/256, BB), blk, 0, stream>>>(rgb, depth, intr, poses, map);

    for (int s = 1; s < LL; ++s) {
        int limit = s*NN;
        k_project<<<dim3((limit+255)/256, BB), blk, 0, stream>>>(intr, poses, map, corr, s);
        k_fuse  <<<dim3((NN+255)/256, BB),    blk, 0, stream>>>(rgb, depth, intr, poses, map, corr, s);
    }
}